// Round 1
// baseline (563.507 us; speedup 1.0000x reference)
//
#include <hip/hip_runtime.h>

#define MM 128
#define NN 128
#define KK 128
#define NBATCH 4
#define ITERS 8
#define WIN 10
#define WSTRIDE 12
#define MNK (MM*NN*KK)

__device__ __forceinline__ float wave_sum(float v) {
  v += __shfl_xor(v, 32, 64);
  v += __shfl_xor(v, 16, 64);
  v += __shfl_xor(v, 8, 64);
  v += __shfl_xor(v, 4, 64);
  v += __shfl_xor(v, 2, 64);
  v += __shfl_xor(v, 1, 64);
  return v;
}

// One workgroup per spatial 8^3 block (4096 blocks). 256 threads:
// thread t -> p = t>>5 (0..7), q = (t>>2)&7 (0..7), r0 = 2*(t&3); each thread
// owns a (1,1,2) micro-tile of interior positions for ALL 4 batches, holding
// 27*2 conv weights in registers across batches+iterations.
// (1,1,2) instead of (1,2,2): 54 persistent weight floats instead of 108 ->
// ~100 VGPR total instead of ~190 (VGPR+AGPR) -> ~2x resident waves/SIMD to
// hide the per-iteration barrier+reduction chains.
__global__ __launch_bounds__(256, 4) void gridnet_kernel(
    const float* __restrict__ weight, const float* __restrict__ bias,
    const float* __restrict__ rscale, const float* __restrict__ x,
    float* __restrict__ out) {
  // window rows padded 10 -> 12 floats: float2-aligned and 2-way-bank-free
  __shared__ __align__(16) float Wl[WIN * WIN * WSTRIDE];
  __shared__ float red[16];

  const int t = threadIdx.x;
  const int r0 = (t & 3) * 2;
  const int q  = (t >> 2) & 7;
  const int p  = t >> 5;

  // XCD-bijective swizzle: 4096 blocks % 8 XCDs == 0, so lx = (bx%8)*512+bx/8
  // gives each XCD a contiguous run of logical ids. Consecutive logical ids
  // differ in bk -> the two blocks sharing each 64B cache line of weight/x
  // land on the SAME XCD's L2 back-to-back (kills the 2x HBM overfetch).
  const int bx = ((blockIdx.x & 7) << 9) | ((int)blockIdx.x >> 3);
  const int bm = bx >> 8, bn = (bx >> 4) & 15, bk = bx & 15;

  const int gm0 = bm * 8, gn0 = bn * 8, gk0 = bk * 8;
  const int baseg = ((gm0 + p) * NN + (gn0 + q)) * KK + (gk0 + r0);

  // per-thread weights: w[dr][o], o = i*9 + j*3 + k
  float w[2][27];
  float S[2] = {0.f, 0.f};
#pragma unroll
  for (int o = 0; o < 27; ++o) {
    float2 wv = *(const float2*)(weight + o * MNK + baseg);
    w[0][o] = wv.x; w[1][o] = wv.y;
    S[0] += wv.x;   S[1] += wv.y;
  }
  float bia[2], rsc[2];
  {
    float2 bv = *(const float2*)(bias + baseg);
    bia[0] = bv.x; bia[1] = bv.y;
    float2 rv = *(const float2*)(rscale + baseg);
    rsc[0] = rv.x; rsc[1] = rv.y;
  }

  for (int b = 0; b < NBATCH; ++b) {
    __syncthreads();  // protect Wl from previous batch's readers
    // ---- load 10^3 window (zero-padded at grid boundary) into LDS ----
    float sA = 0.f, sAq = 0.f, sH = 0.f, sHq = 0.f;
    for (int idx = t; idx < 1000; idx += 256) {
      int wp = idx / 100;
      int rem = idx - wp * 100;
      int wq = rem / 10;
      int wk = rem - wq * 10;
      int gm = gm0 - 1 + wp, gn = gn0 - 1 + wq, gk = gk0 - 1 + wk;
      float v = 0.0f;
      if ((unsigned)gm < 128u && (unsigned)gn < 128u && (unsigned)gk < 128u)
        v = x[((b * MM + gm) * NN + gn) * KK + gk];
      Wl[(wp * WIN + wq) * WSTRIDE + wk] = v;
      sA += v; sAq += v * v;
      // halo (window shell) never changes across iterations: fold once
      if (wp == 0 || wp == 9 || wq == 0 || wq == 9 || wk == 0 || wk == 9) {
        sH += v; sHq += v * v;
      }
    }
    sA = wave_sum(sA); sAq = wave_sum(sAq);
    sH = wave_sum(sH); sHq = wave_sum(sHq);
    if ((t & 63) == 0) {
      int wv_ = t >> 6;
      red[wv_ * 4 + 0] = sA; red[wv_ * 4 + 1] = sAq;
      red[wv_ * 4 + 2] = sH; red[wv_ * 4 + 3] = sHq;
    }
    __syncthreads();
    float totS = red[0] + red[4] + red[8] + red[12];
    float totQ = red[1] + red[5] + red[9] + red[13];
    const float hS = red[2] + red[6] + red[10] + red[14];
    const float hQ = red[3] + red[7] + red[11] + red[15];

    // own interior acts in registers (kept in sync with LDS)
    float a[2];
    a[0] = Wl[((p + 1) * WIN + (q + 1)) * WSTRIDE + (r0 + 1)];
    a[1] = Wl[((p + 1) * WIN + (q + 1)) * WSTRIDE + (r0 + 2)];

    float mu = totS * (1.0f / 1000.0f);
    float var = totQ * (1.0f / 1000.0f) - mu * mu;
    float inv = __builtin_amdgcn_rsqf(var + 1e-5f);

    for (int it = 0; it < ITERS; ++it) {
      // ---- locally-connected 3^3 conv on RAW acts (normalization folded) ----
      float acc[2] = {0.f, 0.f};
#pragma unroll
      for (int i = 0; i < 3; ++i) {
#pragma unroll
        for (int j = 0; j < 3; ++j) {
          // row [r0 .. r0+4) of window row (p+i, q+j): two aligned b64 reads
          const float* bp = &Wl[((p + i) * WIN + (q + j)) * WSTRIDE + r0];
          float2 u0 = *(const float2*)bp;
          float2 u1 = *(const float2*)(bp + 2);
          const float v0 = u0.x, v1 = u0.y, v2 = u1.x, v3 = u1.y;
          const int ob = i * 9 + j * 3;
          acc[0] += w[0][ob + 0] * v0 + w[0][ob + 1] * v1 + w[0][ob + 2] * v2;
          acc[1] += w[1][ob + 0] * v1 + w[1][ob + 1] * v2 + w[1][ob + 2] * v3;
        }
      }
      // acc_final = bias + inv*(conv_raw) - inv*mu*(sum of 27 weights)
      const float im = inv * mu;
#pragma unroll
      for (int dr = 0; dr < 2; ++dr) {
        float z = bia[dr] + inv * acc[dr] - im * S[dr];
        float e = __expf(-z);
        float sg = __builtin_amdgcn_rcpf(1.0f + e);  // sigmoid(z)
        a[dr] += rsc[dr] * (z * sg);                 // residual silu
      }
      if (it < ITERS - 1) {
        __syncthreads();  // all conv reads done before anyone writes
        Wl[((p + 1) * WIN + (q + 1)) * WSTRIDE + (r0 + 1)] = a[0];
        Wl[((p + 1) * WIN + (q + 1)) * WSTRIDE + (r0 + 2)] = a[1];
        float ls = a[0] + a[1];
        float lq = a[0] * a[0] + a[1] * a[1];
        ls = wave_sum(ls); lq = wave_sum(lq);
        if ((t & 63) == 0) { red[(t >> 6) * 2 + 0] = ls; red[(t >> 6) * 2 + 1] = lq; }
        __syncthreads();  // partials ready AND writes visible for next iter reads
        float tS = red[0] + red[2] + red[4] + red[6] + hS;
        float tQ = red[1] + red[3] + red[5] + red[7] + hQ;
        mu = tS * (1.0f / 1000.0f);
        var = tQ * (1.0f / 1000.0f) - mu * mu;
        inv = __builtin_amdgcn_rsqf(var + 1e-5f);
      }
    }
    // ---- write final interior from registers ----
    const int baseo = ((b * MM + gm0 + p) * NN + (gn0 + q)) * KK + (gk0 + r0);
    float2 ov; ov.x = a[0]; ov.y = a[1];
    *(float2*)(out + baseo) = ov;
  }
}

extern "C" void kernel_launch(void* const* d_in, const int* in_sizes, int n_in,
                              void* d_out, int out_size, void* d_ws, size_t ws_size,
                              hipStream_t stream) {
  const float* weight = (const float*)d_in[0];
  const float* bias   = (const float*)d_in[1];
  const float* rscale = (const float*)d_in[2];
  const float* x      = (const float*)d_in[3];
  // d_in[4] = inner_iterations (8), d_in[5] = block_size (8): fixed by harness
  float* out = (float*)d_out;
  gridnet_kernel<<<dim3(16 * 16 * 16), dim3(256), 0, stream>>>(
      weight, bias, rscale, x, out);
}

// Round 2
// 541.359 us; speedup vs baseline: 1.0409x; 1.0409x over previous
//
#include <hip/hip_runtime.h>

#define MM 128
#define NN 128
#define KK 128
#define NBATCH 4
#define ITERS 8
#define WIN 10
#define WSTRIDE 12
#define WSZ (WIN * WIN * WSTRIDE)  // 1200 floats per window buffer
#define MNK (MM * NN * KK)

// One workgroup per spatial 8^3 block (4096 blocks). 128 threads:
// thread t -> p = t>>4 (0..7), q0 = 2*((t>>2)&3), r0 = 2*(t&3); each thread
// owns a (1,2,2) micro-tile for ALL 4 batches, 27*4 conv weights in registers.
// Round-2 structure: double-buffered window -> ONE barrier per inner iter
// (write-after-read hazard gone), stats reduction split so only a 4-step
// shuffle chain sits before the barrier and the 8-way partial sum overlaps
// the next iteration's conv reads.
__global__ __launch_bounds__(128, 2) void gridnet_kernel(
    const float* __restrict__ weight, const float* __restrict__ bias,
    const float* __restrict__ rscale, const float* __restrict__ x,
    float* __restrict__ out) {
  // rows padded 10 -> 12 floats: float2-aligned, 48B row stride
  __shared__ __align__(16) float Wl[2][WSZ];
  __shared__ float red[2][16];  // [iter parity][group*2 + {sum,sumsq}]
  __shared__ float redH[4];     // halo partial per wave

  const int t = threadIdx.x;
  const int r2 = t & 3, q2 = (t >> 2) & 3, p = t >> 4;
  const int r0 = r2 * 2, q0 = q2 * 2;
  const int grp = t >> 4;  // 16-lane group id, 0..7

  // XCD-bijective swizzle (4096 % 8 == 0): consecutive logical ids (adjacent
  // bk, sharing 64B weight/x cache lines) land on the SAME XCD's L2.
  // Round-1 evidence: FETCH_SIZE 575 MB -> 139 MB. Keep it.
  const int bx = ((blockIdx.x & 7) << 9) | ((int)blockIdx.x >> 3);
  const int bm = bx >> 8, bn = (bx >> 4) & 15, bk = bx & 15;

  const int gm0 = bm * 8, gn0 = bn * 8, gk0 = bk * 8;
  const int baseg = ((gm0 + p) * NN + (gn0 + q0)) * KK + (gk0 + r0);

  // per-thread weights: w[dq][dr][o], o = i*9 + j*3 + k
  float w[2][2][27];
  float S[2][2] = {{0.f, 0.f}, {0.f, 0.f}};
#pragma unroll
  for (int dq = 0; dq < 2; ++dq) {
#pragma unroll
    for (int o = 0; o < 27; ++o) {
      float2 wv = *(const float2*)(weight + o * MNK + baseg + dq * KK);
      w[dq][0][o] = wv.x; w[dq][1][o] = wv.y;
      S[dq][0] += wv.x;   S[dq][1] += wv.y;
    }
  }
  float bia[2][2], rsc[2][2];
#pragma unroll
  for (int dq = 0; dq < 2; ++dq) {
    float2 bv = *(const float2*)(bias + baseg + dq * KK);
    bia[dq][0] = bv.x; bia[dq][1] = bv.y;
    float2 rv = *(const float2*)(rscale + baseg + dq * KK);
    rsc[dq][0] = rv.x; rsc[dq][1] = rv.y;
  }

  for (int b = 0; b < NBATCH; ++b) {
    __syncthreads();  // previous batch's last-iter readers done with Wl/red
    // ---- load 10^3 window (zero-padded at boundary) into BOTH buffers ----
    float sI = 0.f, sIq = 0.f, sH = 0.f, sHq = 0.f;
    for (int idx = t; idx < 1000; idx += 128) {
      int wp = idx / 100;
      int rem = idx - wp * 100;
      int wq = rem / 10;
      int wk = rem - wq * 10;
      int gm = gm0 - 1 + wp, gn = gn0 - 1 + wq, gk = gk0 - 1 + wk;
      float v = 0.0f;
      if ((unsigned)gm < 128u && (unsigned)gn < 128u && (unsigned)gk < 128u)
        v = x[((b * MM + gm) * NN + gn) * KK + gk];
      const int adr = (wp * WIN + wq) * WSTRIDE + wk;
      Wl[0][adr] = v;
      Wl[1][adr] = v;  // halo copy; interior of buf1 overwritten by iter 0
      // halo (window shell) is static across iterations
      if (wp == 0 || wp == 9 || wq == 0 || wq == 9 || wk == 0 || wk == 9) {
        sH += v; sHq += v * v;
      } else {
        sI += v; sIq += v * v;
      }
    }
    // interior partials: 4-step reduce to per-16-lane groups
    sI += __shfl_xor(sI, 1, 64); sIq += __shfl_xor(sIq, 1, 64);
    sI += __shfl_xor(sI, 2, 64); sIq += __shfl_xor(sIq, 2, 64);
    sI += __shfl_xor(sI, 4, 64); sIq += __shfl_xor(sIq, 4, 64);
    sI += __shfl_xor(sI, 8, 64); sIq += __shfl_xor(sIq, 8, 64);
    if ((t & 15) == 0) { red[0][grp * 2] = sI; red[0][grp * 2 + 1] = sIq; }
    // halo totals: full 6-step butterfly (once per batch, off hot path)
    sH += __shfl_xor(sH, 32, 64); sHq += __shfl_xor(sHq, 32, 64);
    sH += __shfl_xor(sH, 16, 64); sHq += __shfl_xor(sHq, 16, 64);
    sH += __shfl_xor(sH, 8, 64);  sHq += __shfl_xor(sHq, 8, 64);
    sH += __shfl_xor(sH, 4, 64);  sHq += __shfl_xor(sHq, 4, 64);
    sH += __shfl_xor(sH, 2, 64);  sHq += __shfl_xor(sHq, 2, 64);
    sH += __shfl_xor(sH, 1, 64);  sHq += __shfl_xor(sHq, 1, 64);
    if ((t & 63) == 0) { redH[(t >> 6) * 2] = sH; redH[(t >> 6) * 2 + 1] = sHq; }
    __syncthreads();
    const float hS = redH[0] + redH[2];
    const float hQ = redH[1] + redH[3];

    // own interior acts in registers (kept in sync with current LDS buffer)
    float a[2][2];
#pragma unroll
    for (int dq = 0; dq < 2; ++dq)
#pragma unroll
      for (int dr = 0; dr < 2; ++dr)
        a[dq][dr] = Wl[0][((p + 1) * WIN + (q0 + dq + 1)) * WSTRIDE + (r0 + dr + 1)];

#pragma unroll
    for (int it = 0; it < ITERS; ++it) {
      const int rb = it & 1;        // compile-time (loop unrolled)
      const float* Wc = Wl[rb];
      float* Wn = Wl[rb ^ 1];
      // ---- 3^3 locally-connected conv on RAW acts (norm folded) ----
      float acc[2][2] = {{0.f, 0.f}, {0.f, 0.f}};
#pragma unroll
      for (int i = 0; i < 3; ++i) {
        float v[4][4];
#pragma unroll
        for (int jj = 0; jj < 4; ++jj) {
          const float* bp = &Wc[((p + i) * WIN + (q0 + jj)) * WSTRIDE + r0];
          float2 u0 = *(const float2*)bp;
          float2 u1 = *(const float2*)(bp + 2);
          v[jj][0] = u0.x; v[jj][1] = u0.y; v[jj][2] = u1.x; v[jj][3] = u1.y;
        }
#pragma unroll
        for (int j = 0; j < 3; ++j)
#pragma unroll
          for (int kc = 0; kc < 3; ++kc) {
            const int o = i * 9 + j * 3 + kc;
#pragma unroll
            for (int dq = 0; dq < 2; ++dq) {
              acc[dq][0] += w[dq][0][o] * v[dq + j][kc];
              acc[dq][1] += w[dq][1][o] * v[dq + j][kc + 1];
            }
          }
      }
      // ---- stats for THIS iter: 8 broadcast float2 reads, sunk after conv
      // so their latency hides under the conv's ds_read chain ----
      float tS = hS, tQ = hQ;
#pragma unroll
      for (int g = 0; g < 8; ++g) {
        float2 pr = *(const float2*)&red[rb][g * 2];
        tS += pr.x; tQ += pr.y;
      }
      const float mu = tS * (1.0f / 1000.0f);
      const float var = tQ * (1.0f / 1000.0f) - mu * mu;
      const float inv = __builtin_amdgcn_rsqf(var + 1e-5f);
      const float im = inv * mu;
      // acc_final = bias + inv*conv_raw - inv*mu*(sum of 27 weights)
#pragma unroll
      for (int dq = 0; dq < 2; ++dq)
#pragma unroll
        for (int dr = 0; dr < 2; ++dr) {
          float z = bia[dq][dr] + inv * acc[dq][dr] - im * S[dq][dr];
          float e = __expf(-z);
          float sg = __builtin_amdgcn_rcpf(1.0f + e);  // sigmoid(z)
          a[dq][dr] += rsc[dq][dr] * (z * sg);          // residual silu
        }
      if (it < ITERS - 1) {
        // write own interior to the NEXT buffer (no read hazard: readers of
        // Wn finished before the barrier that ended the previous iteration)
#pragma unroll
        for (int dq = 0; dq < 2; ++dq)
#pragma unroll
          for (int dr = 0; dr < 2; ++dr)
            Wn[((p + 1) * WIN + (q0 + dq + 1)) * WSTRIDE + (r0 + dr + 1)] = a[dq][dr];
        // interior partials for next iter: 4-step chain only
        float ls = a[0][0] + a[0][1] + a[1][0] + a[1][1];
        float lq = a[0][0] * a[0][0] + a[0][1] * a[0][1] +
                   a[1][0] * a[1][0] + a[1][1] * a[1][1];
        ls += __shfl_xor(ls, 1, 64); lq += __shfl_xor(lq, 1, 64);
        ls += __shfl_xor(ls, 2, 64); lq += __shfl_xor(lq, 2, 64);
        ls += __shfl_xor(ls, 4, 64); lq += __shfl_xor(lq, 4, 64);
        ls += __shfl_xor(ls, 8, 64); lq += __shfl_xor(lq, 8, 64);
        if ((t & 15) == 0) { red[rb ^ 1][grp * 2] = ls; red[rb ^ 1][grp * 2 + 1] = lq; }
        __syncthreads();  // the ONLY barrier per iteration
      }
    }
    // ---- write final interior from registers ----
    const int baseo = ((b * MM + gm0 + p) * NN + (gn0 + q0)) * KK + (gk0 + r0);
#pragma unroll
    for (int dq = 0; dq < 2; ++dq) {
      float2 ov; ov.x = a[dq][0]; ov.y = a[dq][1];
      *(float2*)(out + baseo + dq * KK) = ov;
    }
  }
}

extern "C" void kernel_launch(void* const* d_in, const int* in_sizes, int n_in,
                              void* d_out, int out_size, void* d_ws, size_t ws_size,
                              hipStream_t stream) {
  const float* weight = (const float*)d_in[0];
  const float* bias   = (const float*)d_in[1];
  const float* rscale = (const float*)d_in[2];
  const float* x      = (const float*)d_in[3];
  // d_in[4] = inner_iterations (8), d_in[5] = block_size (8): fixed by harness
  float* out = (float*)d_out;
  gridnet_kernel<<<dim3(16 * 16 * 16), dim3(128), 0, stream>>>(
      weight, bias, rscale, x, out);
}